// Round 7
// baseline (26.445 us; speedup 1.0000x reference)
//
#include <hip/hip_runtime.h>

// out[k][j] = max( x1[k][j], max_i( W[i][j]*x0[k][i] + B[i][j] + C_norm[i][j] ) )
// N=4096, D=256, f32 in/out. f16 packed math (validated absmax 0.031 < 0.101).
//
// Round-7 theory: previous designs were capped at 2 waves/SIMD (256 blocks).
// Now: 16-way i-split -> 512 blocks x 512 thr (2 blocks/CU, 4 waves/SIMD),
// VGPR<=128 (audited ~115, no spills), LDS 64KB/block. Block tile 64k x 32j,
// per-thread 8k x 8j. Inner: per 8-i chunk load W/A rows to regs (16 b128),
// then per k-row ONE ds_read_b128 of X feeds 64 pk insts. LDS tree-merge.

typedef _Float16 h16;
typedef h16 h2  __attribute__((ext_vector_type(2)));
typedef h16 h8v __attribute__((ext_vector_type(8)));
typedef float f32x4 __attribute__((ext_vector_type(4)));

constexpr int Dk = 256;
constexpr int NK = 4096;

// ---------------- prep: pure streaming f32 -> f16 converts ----------------
__global__ __launch_bounds__(256)
void prep(const float* __restrict__ x0, const float* __restrict__ Cn,
          const float* __restrict__ W, const float* __restrict__ Bm,
          h16* __restrict__ x0h, h16* __restrict__ Wh, h16* __restrict__ Ah) {
  const int b = blockIdx.x, t = threadIdx.x;
  if (b < 512) {                        // x0: 1M elems, 8/thread
    const int idx = (b * 256 + t) * 8;
    const f32x4 v0 = *reinterpret_cast<const f32x4*>(&x0[idx]);
    const f32x4 v1 = *reinterpret_cast<const f32x4*>(&x0[idx + 4]);
    h8v h;
#pragma unroll
    for (int u = 0; u < 4; ++u) { h[u] = (h16)v0[u]; h[u + 4] = (h16)v1[u]; }
    *reinterpret_cast<h8v*>(&x0h[idx]) = h;
  } else {                              // W, A=B+C: 65536 elems, 8/thread
    const int idx = ((b - 512) * 256 + t) * 8;
    const f32x4 w0 = *reinterpret_cast<const f32x4*>(&W[idx]);
    const f32x4 w1 = *reinterpret_cast<const f32x4*>(&W[idx + 4]);
    const f32x4 b0 = *reinterpret_cast<const f32x4*>(&Bm[idx]);
    const f32x4 b1 = *reinterpret_cast<const f32x4*>(&Bm[idx + 4]);
    const f32x4 c0 = *reinterpret_cast<const f32x4*>(&Cn[idx]);
    const f32x4 c1 = *reinterpret_cast<const f32x4*>(&Cn[idx + 4]);
    const f32x4 a0 = b0 + c0, a1 = b1 + c1;
    h8v hw, ha;
#pragma unroll
    for (int u = 0; u < 4; ++u) {
      hw[u] = (h16)w0[u]; hw[u + 4] = (h16)w1[u];
      ha[u] = (h16)a0[u]; ha[u + 4] = (h16)a1[u];
    }
    *reinterpret_cast<h8v*>(&Wh[idx]) = hw;
    *reinterpret_cast<h8v*>(&Ah[idx]) = ha;
  }
}

// ---------------- main ----------------
__global__ __launch_bounds__(512, 4)       // 4 waves/EU -> 2 blocks/CU, VGPR<=128
void mp_main(const h16* __restrict__ x0h, const h16* __restrict__ Wh,
             const h16* __restrict__ Ah, const float* __restrict__ x1,
             float* __restrict__ out) {
  __shared__ __align__(16) h16 smem[32768];   // 64 KB
  h16* Xl = smem;            // [64 k][256 i]  32KB
  h16* Wl = smem + 16384;    // [256 i][32 j]  16KB
  h16* Al = smem + 24576;    // [256 i][32 j]  16KB

  const int tid = threadIdx.x;
  const int s   = tid >> 5;        // i-slice 0..15 (16 i's each)
  const int t5  = tid & 31;
  const int tk  = t5 >> 2;         // 8 k-rows of 8
  const int tj  = t5 & 3;          // 4 j-groups of 8
  const int k0  = (blockIdx.x >> 3) * 64;
  const int j0  = (blockIdx.x & 7) * 32;

  // ---- stage (once): X 2048 chunks, W/A 1024 chunks each ----
#pragma unroll
  for (int c = 0; c < 4; ++c) {
    const int idx = c * 512 + tid;
    const int row = idx >> 5, ch = (idx & 31) * 8;
    *reinterpret_cast<h8v*>(&Xl[row * 256 + ch]) =
        *reinterpret_cast<const h8v*>(&x0h[(k0 + row) * Dk + ch]);
  }
#pragma unroll
  for (int c = 0; c < 2; ++c) {
    const int idx = c * 512 + tid;
    const int row = idx >> 2, jc = (idx & 3) * 8;
    *reinterpret_cast<h8v*>(&Wl[row * 32 + jc]) =
        *reinterpret_cast<const h8v*>(&Wh[row * Dk + j0 + jc]);
    *reinterpret_cast<h8v*>(&Al[row * 32 + jc]) =
        *reinterpret_cast<const h8v*>(&Ah[row * Dk + j0 + jc]);
  }
  __syncthreads();

  h2 acc[8][4];
#pragma unroll
  for (int kk = 0; kk < 8; ++kk)
#pragma unroll
    for (int p = 0; p < 4; ++p)
      acc[kk][p] = h2{(h16)(-60000.0f), (h16)(-60000.0f)};

#define USTEP(U) {                                                               \
    const h2 xb = __builtin_shufflevector(xv, xv, (U), (U));                     \
    const h2 w0 = __builtin_shufflevector(wv[U], wv[U], 0, 1);                   \
    const h2 w1 = __builtin_shufflevector(wv[U], wv[U], 2, 3);                   \
    const h2 w2 = __builtin_shufflevector(wv[U], wv[U], 4, 5);                   \
    const h2 w3 = __builtin_shufflevector(wv[U], wv[U], 6, 7);                   \
    const h2 a0 = __builtin_shufflevector(av[U], av[U], 0, 1);                   \
    const h2 a1 = __builtin_shufflevector(av[U], av[U], 2, 3);                   \
    const h2 a2 = __builtin_shufflevector(av[U], av[U], 4, 5);                   \
    const h2 a3 = __builtin_shufflevector(av[U], av[U], 6, 7);                   \
    acc[kk][0] = __builtin_elementwise_max(acc[kk][0], __builtin_elementwise_fma(w0, xb, a0)); \
    acc[kk][1] = __builtin_elementwise_max(acc[kk][1], __builtin_elementwise_fma(w1, xb, a1)); \
    acc[kk][2] = __builtin_elementwise_max(acc[kk][2], __builtin_elementwise_fma(w2, xb, a2)); \
    acc[kk][3] = __builtin_elementwise_max(acc[kk][3], __builtin_elementwise_fma(w3, xb, a3)); \
  }

#pragma unroll
  for (int cc = 0; cc < 2; ++cc) {
    const int i0 = s * 16 + cc * 8;
    h8v wv[8], av[8];
#pragma unroll
    for (int u = 0; u < 8; ++u) {
      wv[u] = *reinterpret_cast<const h8v*>(&Wl[(i0 + u) * 32 + tj * 8]);
      av[u] = *reinterpret_cast<const h8v*>(&Al[(i0 + u) * 32 + tj * 8]);
    }
#pragma unroll
    for (int kk = 0; kk < 8; ++kk) {
      const h8v xv = *reinterpret_cast<const h8v*>(&Xl[(tk * 8 + kk) * 256 + i0]);
      USTEP(0) USTEP(1) USTEP(2) USTEP(3) USTEP(4) USTEP(5) USTEP(6) USTEP(7)
    }
  }
#undef USTEP

  __syncthreads();   // all Xl/Wl/Al reads done; reuse as merge scratch

  // ---- tree merge: 16 slices -> 1 (slots [8][32 t5][8 c] uint4, 32KB) ----
  uint4* mrg = reinterpret_cast<uint4*>(smem);
  auto wslot = [&](int slot) {
#pragma unroll
    for (int c = 0; c < 8; ++c) {
      uint4 u;
      u.x = __builtin_bit_cast(unsigned int, acc[c][0]);
      u.y = __builtin_bit_cast(unsigned int, acc[c][1]);
      u.z = __builtin_bit_cast(unsigned int, acc[c][2]);
      u.w = __builtin_bit_cast(unsigned int, acc[c][3]);
      mrg[(slot * 32 + t5) * 8 + (c ^ (t5 & 7))] = u;
    }
  };
  auto rmerge = [&](int slot) {
#pragma unroll
    for (int c = 0; c < 8; ++c) {
      const uint4 u = mrg[(slot * 32 + t5) * 8 + (c ^ (t5 & 7))];
      acc[c][0] = __builtin_elementwise_max(acc[c][0], __builtin_bit_cast(h2, u.x));
      acc[c][1] = __builtin_elementwise_max(acc[c][1], __builtin_bit_cast(h2, u.y));
      acc[c][2] = __builtin_elementwise_max(acc[c][2], __builtin_bit_cast(h2, u.z));
      acc[c][3] = __builtin_elementwise_max(acc[c][3], __builtin_bit_cast(h2, u.w));
    }
  };

  if (s >= 8) wslot(s - 8);
  __syncthreads();
  if (s < 8) rmerge(s);
  __syncthreads();
  if (s >= 4 && s < 8) wslot(s - 4);
  __syncthreads();
  if (s < 4) rmerge(s);
  __syncthreads();
  if (s == 2 || s == 3) wslot(s - 2);
  __syncthreads();
  if (s < 2) rmerge(s);
  __syncthreads();
  if (s == 1) wslot(0);
  __syncthreads();
  if (s == 0) { rmerge(0); wslot(0); }
  __syncthreads();

  // ---- distributed epilogue: thread -> (k = kr, 4 j's), coalesced f32x4 ----
  {
    const int kr  = tid >> 3;                 // 0..63
    const int jq  = tid & 7;                  // 0..7
    const int ot5 = (kr >> 3) * 4 + (jq >> 1);
    const int oc  = kr & 7;
    const uint4 u = mrg[ot5 * 8 + (oc ^ (ot5 & 7))];
    const h2 pa = __builtin_bit_cast(h2, (jq & 1) ? u.z : u.x);
    const h2 pb = __builtin_bit_cast(h2, (jq & 1) ? u.w : u.y);
    const int k = k0 + kr, j = j0 + jq * 4;
    f32x4 o = { (float)pa[0], (float)pa[1], (float)pb[0], (float)pb[1] };
    o = __builtin_elementwise_max(o, *reinterpret_cast<const f32x4*>(&x1[k * Dk + j]));
    *reinterpret_cast<f32x4*>(&out[k * Dk + j]) = o;
  }
}

extern "C" void kernel_launch(void* const* d_in, const int* in_sizes, int n_in,
                              void* d_out, int out_size, void* d_ws, size_t ws_size,
                              hipStream_t stream) {
  const float* x0 = (const float*)d_in[0];
  const float* x1 = (const float*)d_in[1];
  const float* Cn = (const float*)d_in[2];
  const float* W  = (const float*)d_in[3];
  const float* Bm = (const float*)d_in[4];
  float* out = (float*)d_out;

  h16* x0h = (h16*)d_ws;                                          // 2 MB
  h16* Wh  = (h16*)((char*)d_ws + (size_t)NK * Dk * 2);           // 128 KB
  h16* Ah  = (h16*)((char*)d_ws + (size_t)NK * Dk * 2 + Dk * Dk * 2);

  hipLaunchKernelGGL(prep, dim3(512 + 32), dim3(256), 0, stream,
                     x0, Cn, W, Bm, x0h, Wh, Ah);
  hipLaunchKernelGGL(mp_main, dim3((NK / 64) * 8), dim3(512), 0, stream,
                     x0h, Wh, Ah, x1, out);
}